// Round 9
// baseline (132.826 us; speedup 1.0000x reference)
//
#include <hip/hip_runtime.h>
#include <stdint.h>

#define B 8
#define N 8192
#define D 512
#define K 512
#define DIV_W 0.3f
#define UNC_W 0.3f

constexpr int ROWS_PER_WAVE  = 16;
constexpr int WAVES_PER_BLK  = 4;
constexpr int ROWS_PER_BLOCK = ROWS_PER_WAVE * WAVES_PER_BLK;  // 64
constexpr int BLOCKS_PER_B   = N / ROWS_PER_BLOCK;             // 128

constexpr float DIVC = DIV_W * (1.0f + 1.0f / 8191.0f);  // diversity const part
constexpr float COEF = DIV_W / 8191.0f;                  // diversity rs coefficient

// Order-preserving float<->u32 map (monotone)
__device__ __forceinline__ uint32_t ordmap(float f) {
    uint32_t u = __float_as_uint(f);
    return (u & 0x80000000u) ? ~u : (u | 0x80000000u);
}
__device__ __forceinline__ float ordunmap(uint32_t u) {
    return (u >> 31) ? __uint_as_float(u & 0x7FFFFFFFu) : __uint_as_float(~u);
}

// ---------------------------------------------------------------------------
// Pass 1: per-row inverse norm + per-block partial of s[b][d]
//         + entropy/relevance base of combined (no s-dependence)
// ---------------------------------------------------------------------------
__global__ __launch_bounds__(256) void k_norm_s(const float* __restrict__ x,
                                                const float* __restrict__ c,
                                                float* __restrict__ inv_norm,
                                                float* __restrict__ partials,
                                                float* __restrict__ combined) {
    int blk  = blockIdx.x;
    int b    = blk / BLOCKS_PER_B;
    int rb   = (blk % BLOCKS_PER_B) * ROWS_PER_BLOCK;
    int tid  = threadIdx.x;
    int wave = tid >> 6;
    int lane = tid & 63;

    const float4* xb = (const float4*)(x + (size_t)b * N * D);

    float4 accA = {0.f, 0.f, 0.f, 0.f};
    float4 accB = {0.f, 0.f, 0.f, 0.f};

    int row0 = rb + wave * ROWS_PER_WAVE;
    #pragma unroll 4
    for (int r = 0; r < ROWS_PER_WAVE; ++r) {
        int row = row0 + r;
        const float4* xr = xb + (size_t)row * (D / 4);
        float4 a  = xr[lane];
        float4 bb = xr[64 + lane];

        float ss = a.x*a.x + a.y*a.y + a.z*a.z + a.w*a.w
                 + bb.x*bb.x + bb.y*bb.y + bb.z*bb.z + bb.w*bb.w;
        #pragma unroll
        for (int o = 32; o > 0; o >>= 1) ss += __shfl_xor(ss, o, 64);

        float inv = 1.0f / fmaxf(sqrtf(ss), 1e-12f);
        if (lane == 0) inv_norm[b * N + row] = inv;

        accA.x += a.x * inv;  accA.y += a.y * inv;
        accA.z += a.z * inv;  accA.w += a.w * inv;
        accB.x += bb.x * inv; accB.y += bb.y * inv;
        accB.z += bb.z * inv; accB.w += bb.w * inv;
    }

    // entropy + relevance base, 16 lanes in parallel (one row each)
    if (lane < 16) {
        int row = row0 + lane;
        float2 cv = ((const float2*)c)[(size_t)b * N + row];
        float rel = fmaxf(cv.x, cv.y);
        float e0 = expf(cv.x - rel), e1 = expf(cv.y - rel);
        float Z  = e0 + e1;
        float p0 = e0 / Z, p1 = e1 / Z;
        float ent = -(p0 * logf(p0 + 1e-8f) + p1 * logf(p1 + 1e-8f));
        combined[b * N + row] = rel + UNC_W * ent + DIVC;
    }

    __shared__ float sp[WAVES_PER_BLK][D];
    float* dA = &sp[wave][lane * 4];
    dA[0] = accA.x; dA[1] = accA.y; dA[2] = accA.z; dA[3] = accA.w;
    float* dB = &sp[wave][256 + lane * 4];
    dB[0] = accB.x; dB[1] = accB.y; dB[2] = accB.z; dB[3] = accB.w;
    __syncthreads();

    float* dst = partials + (size_t)blk * D;
    for (int d = tid; d < D; d += 256)
        dst[d] = sp[0][d] + sp[1][d] + sp[2][d] + sp[3][d];
}

// ---------------------------------------------------------------------------
// Pass 1b: s[b][d] = sum over the 128 block partials (L2-resident)
// ---------------------------------------------------------------------------
__global__ __launch_bounds__(512) void k_reduce_s(const float* __restrict__ partials,
                                                  float* __restrict__ s) {
    int b = blockIdx.x;
    int d = threadIdx.x;          // 512 == D
    const float* p = partials + (size_t)b * BLOCKS_PER_B * D + d;
    float acc = 0.f;
    #pragma unroll 16
    for (int j = 0; j < BLOCKS_PER_B; ++j) acc += p[(size_t)j * D];
    s[b * D + d] = acc;
}

// ---------------------------------------------------------------------------
// Pass 2: combined[b][n] -= COEF * (x_n . s_b) * inv_norm_n   (in place)
// ---------------------------------------------------------------------------
__global__ __launch_bounds__(256) void k_combined(const float* __restrict__ x,
                                                  const float* __restrict__ inv_norm,
                                                  const float* __restrict__ s,
                                                  float* __restrict__ combined) {
    __shared__ float sl[D];
    int blk  = blockIdx.x;
    int b    = blk / BLOCKS_PER_B;
    int rb   = (blk % BLOCKS_PER_B) * ROWS_PER_BLOCK;
    int tid  = threadIdx.x;
    int wave = tid >> 6;
    int lane = tid & 63;

    for (int d = tid; d < D; d += 256) sl[d] = s[b * D + d];
    __syncthreads();

    const float4* sv = (const float4*)sl;
    float4 sA = sv[lane];
    float4 sB = sv[64 + lane];

    const float4* xb = (const float4*)(x + (size_t)b * N * D);
    int row0 = rb + wave * ROWS_PER_WAVE;
    #pragma unroll 4
    for (int r = 0; r < ROWS_PER_WAVE; ++r) {
        int row = row0 + r;
        const float4* xr = xb + (size_t)row * (D / 4);
        float4 a  = xr[lane];
        float4 bb = xr[64 + lane];

        float dot = a.x*sA.x + a.y*sA.y + a.z*sA.z + a.w*sA.w
                  + bb.x*sB.x + bb.y*sB.y + bb.z*sB.z + bb.w*sB.w;
        #pragma unroll
        for (int o = 32; o > 0; o >>= 1) dot += __shfl_xor(dot, o, 64);

        if (lane == 0) {
            float rs = dot * inv_norm[b * N + row];
            combined[b * N + row] -= COEF * rs;
        }
    }
}

// ---------------------------------------------------------------------------
// Pass 3 (fused): softmax + exact top-K (radix select + rank-by-counting).
// One block of 1024 threads per batch; 8 values/thread in VGPRs.
// PURE FUNCTION of `combined` -> idempotent (launched 3x as a timing probe).
// ---------------------------------------------------------------------------
struct P3 {
    unsigned long long cand[K];   // 4 KB: selected packed keys (unique)
    uint32_t hist[256];
    uint32_t tiew[256];           // tie bitmask, 8192 bits
    uint16_t rnk[2][K];           // 2 KB: half-ranks
    uint32_t wred[16];
    float    fred[16];
    uint32_t sc_prefix, sc_remK, sc_cnt;
};

__global__ __launch_bounds__(1024) void k_topk_sm(const float* __restrict__ combined,
                                                  float* __restrict__ out_idx,
                                                  float* __restrict__ out_w) {
    __shared__ P3 p3;

    const int b    = blockIdx.x;
    const int tid  = threadIdx.x;
    const int lane = tid & 63;
    const int wave = tid >> 6;

    // element index of reg slot q: q<4 -> 4*tid+q ; q>=4 -> 4096+4*tid+(q-4)
    const float4* cb4 = (const float4*)(combined + b * N);
    float4 f0 = cb4[tid];
    float4 f1 = cb4[1024 + tid];

    uint32_t v[8];
    v[0] = ordmap(f0.x); v[1] = ordmap(f0.y); v[2] = ordmap(f0.z); v[3] = ordmap(f0.w);
    v[4] = ordmap(f1.x); v[5] = ordmap(f1.y); v[6] = ordmap(f1.z); v[7] = ordmap(f1.w);

    uint32_t umax = 0;
    #pragma unroll
    for (int q = 0; q < 8; ++q) umax = max(umax, v[q]);
    #pragma unroll
    for (int o = 32; o > 0; o >>= 1) umax = max(umax, __shfl_xor(umax, o, 64));
    if (lane == 0) p3.wred[wave] = umax;
    if (tid == 0) { p3.sc_remK = K; p3.sc_prefix = 0u; p3.sc_cnt = 0u; }
    __syncthreads();
    uint32_t bmax = p3.wred[0];
    #pragma unroll
    for (int q = 1; q < 16; ++q) bmax = max(bmax, p3.wred[q]);
    const float m = ordunmap(bmax);

    // ---- softmax ----------------------------------------------------------
    float e[8];
    float sum = 0.f;
    #pragma unroll
    for (int q = 0; q < 8; ++q) { e[q] = expf(ordunmap(v[q]) - m); sum += e[q]; }
    #pragma unroll
    for (int o = 32; o > 0; o >>= 1) sum += __shfl_xor(sum, o, 64);
    if (lane == 0) p3.fred[wave] = sum;
    __syncthreads();
    float Z = 0.f;
    #pragma unroll
    for (int q = 0; q < 16; ++q) Z += p3.fred[q];
    const float invZ = 1.0f / Z;
    float4* ow = (float4*)(out_w + b * N);
    float4 w0 = {e[0]*invZ, e[1]*invZ, e[2]*invZ, e[3]*invZ};
    float4 w1 = {e[4]*invZ, e[5]*invZ, e[6]*invZ, e[7]*invZ};
    ow[tid]        = w0;
    ow[1024 + tid] = w1;

    // ---- radix select: exact K-th largest u32 key -------------------------
    uint32_t prefix = 0, maskHi = 0;
    for (int p = 3; p >= 0; --p) {
        if (tid < 256) p3.hist[tid] = 0u;
        __syncthreads();
        const int sh = 8 * p;
        if (p == 3) {
            // clustered top byte -> match-any wave aggregation
            #pragma unroll
            for (int q = 0; q < 8; ++q) {
                uint32_t bin = v[q] >> 24;
                bool pred = true;
                unsigned long long todo = ~0ULL;
                while (todo) {
                    int leader = __ffsll(todo) - 1;
                    uint32_t lbin = __shfl(bin, leader, 64);
                    unsigned long long same = __ballot(pred && (bin == lbin));
                    if (lane == leader) atomicAdd(&p3.hist[lbin], (uint32_t)__popcll(same));
                    todo &= ~same;
                    if (bin == lbin) pred = false;
                }
            }
        } else {
            #pragma unroll
            for (int q = 0; q < 8; ++q) {
                if ((v[q] & maskHi) == prefix)
                    atomicAdd(&p3.hist[(v[q] >> sh) & 0xFFu], 1u);
            }
        }
        __syncthreads();
        if (wave == 0) {
            uint32_t cc[4], lsum = 0;
            #pragma unroll
            for (int q = 0; q < 4; ++q) { cc[q] = p3.hist[lane * 4 + q]; lsum += cc[q]; }
            uint32_t ssum = lsum;     // suffix-inclusive sum over lanes >= l
            #pragma unroll
            for (int off = 1; off < 64; off <<= 1) {
                uint32_t t2 = __shfl_down(ssum, off, 64);
                if (lane + off < 64) ssum += t2;
            }
            uint32_t cum = ssum - lsum;
            const uint32_t remK = p3.sc_remK;
            #pragma unroll
            for (int q = 3; q >= 0; --q) {
                if (cum < remK && cum + cc[q] >= remK) {
                    p3.sc_prefix = prefix | ((uint32_t)(lane * 4 + q) << sh);
                    p3.sc_remK   = remK - cum;
                }
                cum += cc[q];
            }
        }
        __syncthreads();
        prefix = p3.sc_prefix;
        maskHi |= (0xFFu << sh);
    }
    const uint32_t T    = prefix;    // exact K-th largest value (ord space)
    const uint32_t remF = p3.sc_remK;

    // ---- compaction: strictly-greater (ballot) + tie bitmask --------------
    if (tid < 256) p3.tiew[tid] = 0u;
    __syncthreads();
    #pragma unroll
    for (int q = 0; q < 8; ++q) {
        uint32_t idx = (q < 4) ? (uint32_t)(4 * tid + q)
                               : (uint32_t)(4096 + 4 * tid + (q - 4));
        bool g = (v[q] > T);
        unsigned long long mask = __ballot(g);
        if (mask) {
            int leader = __ffsll(mask) - 1;
            uint32_t bcnt = (uint32_t)__popcll(mask);
            uint32_t wbase = 0;
            if (lane == leader) wbase = atomicAdd(&p3.sc_cnt, bcnt);
            wbase = __shfl(wbase, leader, 64);
            if (g) {
                uint32_t off = (uint32_t)__popcll(mask & ((1ULL << lane) - 1ULL));
                p3.cand[wbase + off] = ((uint64_t)v[q] << 13) | (uint32_t)(8191 - idx);
            }
        }
        if (v[q] == T) atomicOr(&p3.tiew[idx >> 5], 1u << (idx & 31));
    }
    __syncthreads();
    const uint32_t base = p3.sc_cnt;     // == K - remF
    if (wave == 0) {
        const int w0i = lane * 4;
        uint32_t lsum = 0;
        #pragma unroll
        for (int q = 0; q < 4; ++q) lsum += __popc(p3.tiew[w0i + q]);
        uint32_t ssum = lsum;             // inclusive ascending prefix
        #pragma unroll
        for (int off = 1; off < 64; off <<= 1) {
            uint32_t t2 = __shfl_up(ssum, off, 64);
            if (lane >= off) ssum += t2;
        }
        uint32_t rank = ssum - lsum;      // exclusive prefix
        for (int q = 0; q < 4; ++q) {
            uint32_t word = p3.tiew[w0i + q];
            while (word) {
                int bpos = __builtin_ctz(word);
                if (rank < remF) {
                    uint32_t idx = (uint32_t)(w0i + q) * 32u + (uint32_t)bpos;
                    p3.cand[base + rank] = ((uint64_t)T << 13) | (uint32_t)(8191 - idx);
                }
                rank++;
                word &= word - 1;
            }
        }
    }
    __syncthreads();

    // ---- rank-by-counting: 512 unique keys -> descending positions --------
    {
        const int ki   = tid & 511;
        const int half = tid >> 9;
        const uint64_t me = p3.cand[ki];
        const int j0 = half * 256;
        uint32_t cnt = 0;
        #pragma unroll 8
        for (int j = 0; j < 256; ++j)
            cnt += (p3.cand[j0 + j] > me) ? 1u : 0u;
        p3.rnk[half][ki] = (uint16_t)cnt;
    }
    __syncthreads();
    if (tid < K) {
        uint32_t rank = (uint32_t)p3.rnk[0][tid] + (uint32_t)p3.rnk[1][tid];
        uint32_t idx  = 8191u - (uint32_t)(p3.cand[tid] & 0x1FFFu);
        out_idx[b * K + rank] = (float)idx;
    }
}

// ---------------------------------------------------------------------------
extern "C" void kernel_launch(void* const* d_in, const int* in_sizes, int n_in,
                              void* d_out, int out_size, void* d_ws, size_t ws_size,
                              hipStream_t stream) {
    const float* x = (const float*)d_in[0];
    const float* c = (const float*)d_in[1];

    float* ws       = (float*)d_ws;
    float* partials = ws;                              // B*128*D = 524288 floats (2 MB)
    float* s        = partials + B * BLOCKS_PER_B * D; // B*D     = 4096
    float* inv_norm = s + B * D;                       // B*N     = 65536
    float* combined = inv_norm + B * N;                // B*N     = 65536

    float* out = (float*)d_out;                        // [B*K indices][B*N weights]

    k_norm_s  <<<B * BLOCKS_PER_B, 256, 0, stream>>>(x, c, inv_norm, partials, combined);
    k_reduce_s<<<B, 512, 0, stream>>>(partials, s);
    k_combined<<<B * BLOCKS_PER_B, 256, 0, stream>>>(x, inv_norm, s, combined);
    // TIMING PROBE: k_topk_sm is a pure function of `combined`; launching it
    // 3x is deterministic and idempotent. dur(R9) = dur(R8) + 2*t_topk.
    k_topk_sm <<<B, 1024, 0, stream>>>(combined, out, out + B * K);
    k_topk_sm <<<B, 1024, 0, stream>>>(combined, out, out + B * K);
    k_topk_sm <<<B, 1024, 0, stream>>>(combined, out, out + B * K);
}

// Round 10
// 79.730 us; speedup vs baseline: 1.6660x; 1.6660x over previous
//
#include <hip/hip_runtime.h>
#include <stdint.h>

#define B 8
#define N 8192
#define D 512
#define K 512
#define DIV_W 0.3f
#define UNC_W 0.3f

constexpr int ROWS_PER_WAVE  = 16;
constexpr int WAVES_PER_BLK  = 4;
constexpr int ROWS_PER_BLOCK = ROWS_PER_WAVE * WAVES_PER_BLK;  // 64
constexpr int BLOCKS_PER_B   = N / ROWS_PER_BLOCK;             // 128

constexpr float DIVC = DIV_W * (1.0f + 1.0f / 8191.0f);  // diversity const part
constexpr float COEF = DIV_W / 8191.0f;                  // diversity rs coefficient

// Order-preserving float<->u32 map (monotone)
__device__ __forceinline__ uint32_t ordmap(float f) {
    uint32_t u = __float_as_uint(f);
    return (u & 0x80000000u) ? ~u : (u | 0x80000000u);
}
__device__ __forceinline__ float ordunmap(uint32_t u) {
    return (u >> 31) ? __uint_as_float(u & 0x7FFFFFFFu) : __uint_as_float(~u);
}

// ---------------------------------------------------------------------------
// Pass 1: per-row inverse norm + atomic accumulation of s[b][d]
//         + entropy/relevance base of combined (no s-dependence)
// ---------------------------------------------------------------------------
__global__ __launch_bounds__(256) void k_norm_s(const float* __restrict__ x,
                                                const float* __restrict__ c,
                                                float* __restrict__ inv_norm,
                                                float* __restrict__ s,
                                                float* __restrict__ combined) {
    int blk  = blockIdx.x;
    int b    = blk / BLOCKS_PER_B;
    int rb   = (blk % BLOCKS_PER_B) * ROWS_PER_BLOCK;
    int tid  = threadIdx.x;
    int wave = tid >> 6;
    int lane = tid & 63;

    const float4* xb = (const float4*)(x + (size_t)b * N * D);

    float4 accA = {0.f, 0.f, 0.f, 0.f};
    float4 accB = {0.f, 0.f, 0.f, 0.f};

    int row0 = rb + wave * ROWS_PER_WAVE;
    #pragma unroll 4
    for (int r = 0; r < ROWS_PER_WAVE; ++r) {
        int row = row0 + r;
        const float4* xr = xb + (size_t)row * (D / 4);
        float4 a  = xr[lane];
        float4 bb = xr[64 + lane];

        float ss = a.x*a.x + a.y*a.y + a.z*a.z + a.w*a.w
                 + bb.x*bb.x + bb.y*bb.y + bb.z*bb.z + bb.w*bb.w;
        #pragma unroll
        for (int o = 32; o > 0; o >>= 1) ss += __shfl_xor(ss, o, 64);

        float inv = 1.0f / fmaxf(sqrtf(ss), 1e-12f);
        if (lane == 0) inv_norm[b * N + row] = inv;

        accA.x += a.x * inv;  accA.y += a.y * inv;
        accA.z += a.z * inv;  accA.w += a.w * inv;
        accB.x += bb.x * inv; accB.y += bb.y * inv;
        accB.z += bb.z * inv; accB.w += bb.w * inv;
    }

    // entropy + relevance base, 16 lanes in parallel (one row each)
    if (lane < 16) {
        int row = row0 + lane;
        float2 cv = ((const float2*)c)[(size_t)b * N + row];
        float rel = fmaxf(cv.x, cv.y);
        float e0 = expf(cv.x - rel), e1 = expf(cv.y - rel);
        float Z  = e0 + e1;
        float p0 = e0 / Z, p1 = e1 / Z;
        float ent = -(p0 * logf(p0 + 1e-8f) + p1 * logf(p1 + 1e-8f));
        combined[b * N + row] = rel + UNC_W * ent + DIVC;
    }

    __shared__ float sp[WAVES_PER_BLK][D];
    float* dA = &sp[wave][lane * 4];
    dA[0] = accA.x; dA[1] = accA.y; dA[2] = accA.z; dA[3] = accA.w;
    float* dB = &sp[wave][256 + lane * 4];
    dB[0] = accB.x; dB[1] = accB.y; dB[2] = accB.z; dB[3] = accB.w;
    __syncthreads();

    for (int d = tid; d < D; d += 256) {
        float v = sp[0][d] + sp[1][d] + sp[2][d] + sp[3][d];
        atomicAdd(&s[b * D + d], v);
    }
}

// ---------------------------------------------------------------------------
// Pass 2: combined[b][n] -= COEF * (x_n . s_b) * inv_norm_n   (in place)
// ---------------------------------------------------------------------------
__global__ __launch_bounds__(256) void k_combined(const float* __restrict__ x,
                                                  const float* __restrict__ inv_norm,
                                                  const float* __restrict__ s,
                                                  float* __restrict__ combined) {
    __shared__ float sl[D];
    int blk  = blockIdx.x;
    int b    = blk / BLOCKS_PER_B;
    int rb   = (blk % BLOCKS_PER_B) * ROWS_PER_BLOCK;
    int tid  = threadIdx.x;
    int wave = tid >> 6;
    int lane = tid & 63;

    for (int d = tid; d < D; d += 256) sl[d] = s[b * D + d];
    __syncthreads();

    const float4* sv = (const float4*)sl;
    float4 sA = sv[lane];
    float4 sB = sv[64 + lane];

    const float4* xb = (const float4*)(x + (size_t)b * N * D);
    int row0 = rb + wave * ROWS_PER_WAVE;
    #pragma unroll 4
    for (int r = 0; r < ROWS_PER_WAVE; ++r) {
        int row = row0 + r;
        const float4* xr = xb + (size_t)row * (D / 4);
        float4 a  = xr[lane];
        float4 bb = xr[64 + lane];

        float dot = a.x*sA.x + a.y*sA.y + a.z*sA.z + a.w*sA.w
                  + bb.x*sB.x + bb.y*sB.y + bb.z*sB.z + bb.w*sB.w;
        #pragma unroll
        for (int o = 32; o > 0; o >>= 1) dot += __shfl_xor(dot, o, 64);

        if (lane == 0) {
            float rs = dot * inv_norm[b * N + row];
            combined[b * N + row] -= COEF * rs;
        }
    }
}

// ---------------------------------------------------------------------------
// Pass 3 (fused): softmax + exact top-K (radix select + register bitonic).
// One block of 1024 threads per batch; 8 values/thread in VGPRs.
// ---------------------------------------------------------------------------
struct P3 {
    unsigned long long cand[K];   // 4 KB: selected packed keys (unique)
    uint32_t hist[256];
    uint32_t tiew[256];           // tie bitmask, 8192 bits
    uint32_t wred[16];
    float    fred[16];
    uint32_t sc_prefix, sc_remK, sc_cnt;
};

__global__ __launch_bounds__(1024) void k_topk_sm(const float* __restrict__ combined,
                                                  float* __restrict__ out_idx,
                                                  float* __restrict__ out_w) {
    __shared__ P3 p3;

    const int b    = blockIdx.x;
    const int tid  = threadIdx.x;
    const int lane = tid & 63;
    const int wave = tid >> 6;

    // element index of reg slot q: q<4 -> 4*tid+q ; q>=4 -> 4096+4*tid+(q-4)
    const float4* cb4 = (const float4*)(combined + b * N);
    float4 f0 = cb4[tid];
    float4 f1 = cb4[1024 + tid];

    uint32_t v[8];
    v[0] = ordmap(f0.x); v[1] = ordmap(f0.y); v[2] = ordmap(f0.z); v[3] = ordmap(f0.w);
    v[4] = ordmap(f1.x); v[5] = ordmap(f1.y); v[6] = ordmap(f1.z); v[7] = ordmap(f1.w);

    uint32_t umax = 0;
    #pragma unroll
    for (int q = 0; q < 8; ++q) umax = max(umax, v[q]);
    #pragma unroll
    for (int o = 32; o > 0; o >>= 1) umax = max(umax, __shfl_xor(umax, o, 64));
    if (lane == 0) p3.wred[wave] = umax;
    if (tid == 0) { p3.sc_remK = K; p3.sc_prefix = 0u; p3.sc_cnt = 0u; }
    __syncthreads();
    uint32_t bmax = p3.wred[0];
    #pragma unroll
    for (int q = 1; q < 16; ++q) bmax = max(bmax, p3.wred[q]);
    const float m = ordunmap(bmax);

    // ---- softmax (fast-path exp: error ~1e-7 rel, weights ~1e-4 abs) ------
    float e[8];
    float sum = 0.f;
    #pragma unroll
    for (int q = 0; q < 8; ++q) { e[q] = __expf(ordunmap(v[q]) - m); sum += e[q]; }
    #pragma unroll
    for (int o = 32; o > 0; o >>= 1) sum += __shfl_xor(sum, o, 64);
    if (lane == 0) p3.fred[wave] = sum;
    __syncthreads();
    float Z = 0.f;
    #pragma unroll
    for (int q = 0; q < 16; ++q) Z += p3.fred[q];
    const float invZ = 1.0f / Z;
    float4* ow = (float4*)(out_w + b * N);
    float4 w0 = {e[0]*invZ, e[1]*invZ, e[2]*invZ, e[3]*invZ};
    float4 w1 = {e[4]*invZ, e[5]*invZ, e[6]*invZ, e[7]*invZ};
    ow[tid]        = w0;
    ow[1024 + tid] = w1;

    // ---- radix select: exact K-th largest u32 key -------------------------
    uint32_t prefix = 0, maskHi = 0;
    for (int p = 3; p >= 0; --p) {
        if (tid < 256) p3.hist[tid] = 0u;
        __syncthreads();
        const int sh = 8 * p;
        if (p == 3) {
            // clustered top byte -> match-any wave aggregation
            #pragma unroll
            for (int q = 0; q < 8; ++q) {
                uint32_t bin = v[q] >> 24;
                bool pred = true;
                unsigned long long todo = ~0ULL;
                while (todo) {
                    int leader = __ffsll(todo) - 1;
                    uint32_t lbin = __shfl(bin, leader, 64);
                    unsigned long long same = __ballot(pred && (bin == lbin));
                    if (lane == leader) atomicAdd(&p3.hist[lbin], (uint32_t)__popcll(same));
                    todo &= ~same;
                    if (bin == lbin) pred = false;
                }
            }
        } else {
            #pragma unroll
            for (int q = 0; q < 8; ++q) {
                if ((v[q] & maskHi) == prefix)
                    atomicAdd(&p3.hist[(v[q] >> sh) & 0xFFu], 1u);
            }
        }
        __syncthreads();
        if (wave == 0) {
            uint32_t cc[4], lsum = 0;
            #pragma unroll
            for (int q = 0; q < 4; ++q) { cc[q] = p3.hist[lane * 4 + q]; lsum += cc[q]; }
            uint32_t ssum = lsum;     // suffix-inclusive sum over lanes >= l
            #pragma unroll
            for (int off = 1; off < 64; off <<= 1) {
                uint32_t t2 = __shfl_down(ssum, off, 64);
                if (lane + off < 64) ssum += t2;
            }
            uint32_t cum = ssum - lsum;
            const uint32_t remK = p3.sc_remK;
            #pragma unroll
            for (int q = 3; q >= 0; --q) {
                if (cum < remK && cum + cc[q] >= remK) {
                    p3.sc_prefix = prefix | ((uint32_t)(lane * 4 + q) << sh);
                    p3.sc_remK   = remK - cum;
                }
                cum += cc[q];
            }
        }
        __syncthreads();
        prefix = p3.sc_prefix;
        maskHi |= (0xFFu << sh);
    }
    const uint32_t T    = prefix;    // exact K-th largest value (ord space)
    const uint32_t remF = p3.sc_remK;

    // ---- compaction: strictly-greater (ballot) + tie bitmask --------------
    if (tid < 256) p3.tiew[tid] = 0u;
    __syncthreads();
    #pragma unroll
    for (int q = 0; q < 8; ++q) {
        uint32_t idx = (q < 4) ? (uint32_t)(4 * tid + q)
                               : (uint32_t)(4096 + 4 * tid + (q - 4));
        bool g = (v[q] > T);
        unsigned long long mask = __ballot(g);
        if (mask) {
            int leader = __ffsll(mask) - 1;
            uint32_t bcnt = (uint32_t)__popcll(mask);
            uint32_t wbase = 0;
            if (lane == leader) wbase = atomicAdd(&p3.sc_cnt, bcnt);
            wbase = __shfl(wbase, leader, 64);
            if (g) {
                uint32_t off = (uint32_t)__popcll(mask & ((1ULL << lane) - 1ULL));
                p3.cand[wbase + off] = ((uint64_t)v[q] << 13) | (uint32_t)(8191 - idx);
            }
        }
        if (v[q] == T) atomicOr(&p3.tiew[idx >> 5], 1u << (idx & 31));
    }
    __syncthreads();
    const uint32_t base = p3.sc_cnt;     // == K - remF
    if (wave == 0) {
        const int w0i = lane * 4;
        uint32_t lsum = 0;
        #pragma unroll
        for (int q = 0; q < 4; ++q) lsum += __popc(p3.tiew[w0i + q]);
        uint32_t ssum = lsum;             // inclusive ascending prefix
        #pragma unroll
        for (int off = 1; off < 64; off <<= 1) {
            uint32_t t2 = __shfl_up(ssum, off, 64);
            if (lane >= off) ssum += t2;
        }
        uint32_t rank = ssum - lsum;      // exclusive prefix
        for (int q = 0; q < 4; ++q) {
            uint32_t word = p3.tiew[w0i + q];
            while (word) {
                int bpos = __builtin_ctz(word);
                if (rank < remF) {
                    uint32_t idx = (uint32_t)(w0i + q) * 32u + (uint32_t)bpos;
                    p3.cand[base + rank] = ((uint64_t)T << 13) | (uint32_t)(8191 - idx);
                }
                rank++;
                word &= word - 1;
            }
        }
    }
    __syncthreads();

    // ---- bitonic sort of 512 unique keys, descending (register-resident) --
    uint64_t sv = (tid < K) ? p3.cand[tid] : 0ULL;
    __syncthreads();
    for (int k = 2; k <= K; k <<= 1) {
        for (int j = k >> 1; j > 0; j >>= 1) {
            const bool desc  = ((tid & k) == 0);
            const bool lower = ((tid & j) == 0);
            uint64_t pv;
            if (j >= 64) {
                if (tid < K) p3.cand[tid] = sv;
                __syncthreads();
                pv = (tid < K) ? p3.cand[tid ^ j] : 0ULL;
                __syncthreads();
            } else {
                pv = __shfl_xor(sv, j, 64);
            }
            const bool keepmax = (lower == desc);
            if (tid < K && (keepmax ? (pv > sv) : (pv < sv))) sv = pv;
        }
    }
    if (tid < K)
        out_idx[b * K + tid] = (float)(8191u - (uint32_t)(sv & 0x1FFFu));
}

// ---------------------------------------------------------------------------
extern "C" void kernel_launch(void* const* d_in, const int* in_sizes, int n_in,
                              void* d_out, int out_size, void* d_ws, size_t ws_size,
                              hipStream_t stream) {
    const float* x = (const float*)d_in[0];
    const float* c = (const float*)d_in[1];

    float* ws       = (float*)d_ws;
    float* s        = ws;                              // B*D = 4096 floats (16 KB)
    float* inv_norm = s + B * D;                       // B*N = 65536
    float* combined = inv_norm + B * N;                // B*N = 65536

    float* out = (float*)d_out;                        // [B*K indices][B*N weights]

    hipMemsetAsync(s, 0, B * D * sizeof(float), stream);
    k_norm_s  <<<B * BLOCKS_PER_B, 256, 0, stream>>>(x, c, inv_norm, s, combined);
    k_combined<<<B * BLOCKS_PER_B, 256, 0, stream>>>(x, inv_norm, s, combined);
    k_topk_sm <<<B, 1024, 0, stream>>>(combined, out, out + B * K);
}